// Round 1
// baseline (1331.781 us; speedup 1.0000x reference)
//
#include <hip/hip_runtime.h>
#include <hip/hip_bf16.h>
#include <cstdint>

typedef float     f32x4  __attribute__((ext_vector_type(4)));
typedef __bf16    bf16x8 __attribute__((ext_vector_type(8)));
typedef unsigned short u16x4 __attribute__((ext_vector_type(4)));
typedef unsigned short u16x8 __attribute__((ext_vector_type(8)));
typedef unsigned int   u32x4 __attribute__((ext_vector_type(4)));
typedef unsigned short u16;

#define DI __device__ __forceinline__

DI float b2f(u16 u) { union { unsigned int i; float f; } x; x.i = ((unsigned int)u) << 16; return x.f; }
DI u16 f2b(float f) {
  union { float f; unsigned int i; } x; x.f = f;
  return (u16)((x.i + 0x7FFFu + ((x.i >> 16) & 1u)) >> 16);   // RNE
}

// ---------------------------------------------------------------------------
// Transpose + fp32->bf16 convert: src (R x C) f32 row-major -> dst (C x R) bf16
// ---------------------------------------------------------------------------
__global__ __launch_bounds__(256) void tpose_f32_bf16_kernel(
    const float* __restrict__ src, u16* __restrict__ dst, int R, int C)
{
  __shared__ float tile[32][33];
  const int c0 = blockIdx.x * 32, r0 = blockIdx.y * 32;
  const int tx = threadIdx.x, ty = threadIdx.y;
  #pragma unroll
  for (int i = 0; i < 4; ++i)
    tile[ty + i * 8][tx] = src[(long)(r0 + ty + i * 8) * C + c0 + tx];
  __syncthreads();
  #pragma unroll
  for (int i = 0; i < 4; ++i)
    dst[(long)(c0 + ty + i * 8) * R + r0 + tx] = f2b(tile[tx][ty + i * 8]);
}

// ---------------------------------------------------------------------------
// LayerNorm (row of 2048) fp32 -> bf16.  grid = B*S rows, 256 threads.
// ---------------------------------------------------------------------------
__global__ __launch_bounds__(256) void ln_bf16_kernel(
    const float* __restrict__ x, const float* __restrict__ gamma,
    const float* __restrict__ beta, u16* __restrict__ out)
{
  const long row = blockIdx.x;
  const float* xr = x + row * 2048;
  const int tid = threadIdx.x;
  float4 a = *(const float4*)(xr + tid * 8);
  float4 b = *(const float4*)(xr + tid * 8 + 4);
  float s  = a.x + a.y + a.z + a.w + b.x + b.y + b.z + b.w;
  float ss = a.x*a.x + a.y*a.y + a.z*a.z + a.w*a.w
           + b.x*b.x + b.y*b.y + b.z*b.z + b.w*b.w;
  #pragma unroll
  for (int off = 1; off < 64; off <<= 1) { s += __shfl_xor(s, off); ss += __shfl_xor(ss, off); }
  __shared__ float red[8];
  if ((tid & 63) == 0) { red[tid >> 6] = s; red[4 + (tid >> 6)] = ss; }
  __syncthreads();
  s  = red[0] + red[1] + red[2] + red[3];
  ss = red[4] + red[5] + red[6] + red[7];
  const float mu = s * (1.0f / 2048.0f);
  const float rs = rsqrtf(ss * (1.0f / 2048.0f) - mu * mu + 1e-5f);
  const float v[8] = {a.x, a.y, a.z, a.w, b.x, b.y, b.z, b.w};
  u16x8 o;
  #pragma unroll
  for (int j = 0; j < 8; ++j) {
    const int col = tid * 8 + j;
    o[j] = f2b((v[j] - mu) * rs * gamma[col] + beta[col]);
  }
  *(u16x8*)(out + row * 2048 + tid * 8) = o;
}

// ---------------------------------------------------------------------------
// ksum[d_row] = sum_s kT[d_row][s]   (kT rows contiguous, 2048 long, bf16)
// one wave per row; grid = 8192/4 rows
// ---------------------------------------------------------------------------
__global__ __launch_bounds__(256) void ksum_kernel(
    const u16* __restrict__ kT, float* __restrict__ ksum)
{
  const int gw = blockIdx.x * 4 + (threadIdx.x >> 6);
  const int lane = threadIdx.x & 63;
  const u16* r = kT + (long)gw * 2048;
  float s = 0.f;
  #pragma unroll
  for (int j = 0; j < 4; ++j) {
    u16x8 v = *(const u16x8*)(r + j * 512 + lane * 8);
    #pragma unroll
    for (int e = 0; e < 8; ++e) s += b2f(v[e]);
  }
  #pragma unroll
  for (int off = 1; off < 64; off <<= 1) s += __shfl_xor(s, off);
  if (lane == 0) ksum[gw] = s;
}

// ---------------------------------------------------------------------------
// den[b][h][s] = dot(q[b][s][h*128:(h+1)*128], ksum[b][h][:])
// one block per token (b*2048+s); thread t covers head t>>4, 8 elems.
// ---------------------------------------------------------------------------
__global__ __launch_bounds__(256) void den_kernel(
    const u16* __restrict__ q, const float* __restrict__ ksum, float* __restrict__ den)
{
  const long m = blockIdx.x;            // b*2048 + s
  const int tid = threadIdx.x;
  const int b = (int)(m >> 11);
  const int h = tid >> 4;
  const int dl = (tid & 15) * 8;
  const u16* qr = q + m * 2048 + h * 128 + dl;
  const float* ks = ksum + ((long)b * 16 + h) * 128 + dl;
  u16x8 v = *(const u16x8*)qr;
  float s = 0.f;
  #pragma unroll
  for (int e = 0; e < 8; ++e) s += b2f(v[e]) * ks[e];
  #pragma unroll
  for (int off = 1; off < 16; off <<= 1) s += __shfl_xor(s, off);
  if ((tid & 15) == 0) den[((long)b * 16 + h) * 2048 + (m & 2047)] = s;
}

// ---------------------------------------------------------------------------
// fp32 -> bf16 elementwise (t3)
// ---------------------------------------------------------------------------
__global__ __launch_bounds__(256) void cvt_f32_bf16_kernel(
    const float* __restrict__ src, u16* __restrict__ dst, long n)
{
  long i = ((long)blockIdx.x * 256 + threadIdx.x) * 4;
  if (i >= n) return;
  float4 v = *(const float4*)(src + i);
  u16x4 o; o[0] = f2b(v.x); o[1] = f2b(v.y); o[2] = f2b(v.z); o[3] = f2b(v.w);
  *(u16x4*)(dst + i) = o;
}

// ---------------------------------------------------------------------------
// bt-GEMM: C[m][n] = sum_k A[m][k] * Bt[n][k]   (A,Bt bf16 K-major, fp32 acc)
// tile 128x128, BK=64, 256 threads (4 waves, 2x2, each 64x64 = 4x4 MFMA tiles)
// LDS XOR-swizzle (T2): byte ^= (row&7)<<4, both write & read side.
// ACT: 0 none, 1 elu+1, 2 tanh-gelu. OUTMODE: 0 bf16, 1 f32, 2 bf16-transposed
// (attention (B,H,HD,S) layout). RESID: +resid[f32]. ACCUM: +C_old[f32].
// DIVDEN: val /= (den[row]+1e-6).
// ---------------------------------------------------------------------------
template<int ACT, int OUTMODE, int RESID, int ACCUM, int DIVDEN>
__global__ __launch_bounds__(256) void btgemm_kernel(
    const u16* __restrict__ A, const u16* __restrict__ Bt, void* Cv,
    const float* __restrict__ bias, const float* resid, const float* __restrict__ den,
    int M, int N, int K, int lda, int ldb, int ldc, int ZMOD,
    long sAh, long sAl, long sBh, long sBl, long sCh, long sCl, long sDh, long sDl)
{
  __shared__ char lds[32768];
  char* As = lds;
  char* Bs = lds + 16384;
  const int tid = threadIdx.x;
  const int wave = tid >> 6, lane = tid & 63;
  const int lr = lane & 15, lk = lane >> 4;
  const int wr = wave >> 1, wc = wave & 1;
  const int z = blockIdx.z;
  const int zh = z / ZMOD, zl = z % ZMOD;
  const u16* Ab = A + zh * sAh + zl * sAl + (long)blockIdx.x * 128 * lda;
  const u16* Bb = Bt + zh * sBh + zl * sBl + (long)blockIdx.y * 128 * ldb;
  const int sr0 = tid >> 3;            // 0..31 : row within 32-row chunk group
  const int sc0 = (tid & 7) * 8;       // element col (8 bf16 = 16B)

  f32x4 acc[4][4] = {};

  for (int k0 = 0; k0 < K; k0 += 64) {
    #pragma unroll
    for (int i = 0; i < 4; ++i) {
      const int row = i * 32 + sr0;
      u32x4 va = *(const u32x4*)(Ab + (long)row * lda + k0 + sc0);
      u32x4 vb = *(const u32x4*)(Bb + (long)row * ldb + k0 + sc0);
      const int swz = (sc0 * 2) ^ ((row & 7) << 4);
      *(u32x4*)(As + row * 128 + swz) = va;
      *(u32x4*)(Bs + row * 128 + swz) = vb;
    }
    __syncthreads();
    #pragma unroll
    for (int kk = 0; kk < 64; kk += 32) {
      bf16x8 af[4], bf[4];
      #pragma unroll
      for (int m = 0; m < 4; ++m) {
        const int row = wr * 64 + m * 16 + lr;
        af[m] = *(const bf16x8*)(As + row * 128 + (((kk + lk * 8) * 2) ^ ((row & 7) << 4)));
      }
      #pragma unroll
      for (int n = 0; n < 4; ++n) {
        const int row = wc * 64 + n * 16 + lr;
        bf[n] = *(const bf16x8*)(Bs + row * 128 + (((kk + lk * 8) * 2) ^ ((row & 7) << 4)));
      }
      #pragma unroll
      for (int m = 0; m < 4; ++m)
        #pragma unroll
        for (int n = 0; n < 4; ++n)
          acc[m][n] = __builtin_amdgcn_mfma_f32_16x16x32_bf16(af[m], bf[n], acc[m][n], 0, 0, 0);
    }
    __syncthreads();
  }

  const long cbase = (long)zh * sCh + (long)zl * sCl;
  #pragma unroll
  for (int m = 0; m < 4; ++m) {
    #pragma unroll
    for (int n = 0; n < 4; ++n) {
      const int gm0 = blockIdx.x * 128 + wr * 64 + m * 16 + lk * 4;
      const int gn  = blockIdx.y * 128 + wc * 64 + n * 16 + lr;
      float v4[4];
      #pragma unroll
      for (int i = 0; i < 4; ++i) {
        float val = acc[m][n][i];
        if (bias) val += bias[gn];
        if (ACT == 1) val = (val > 0.f) ? (val + 1.f) : expf(val);
        if (ACT == 2) {
          const float u = val;
          const float t = tanhf(0.7978845608028654f * (u + 0.044715f * u * u * u));
          val = 0.5f * u * (1.0f + t);
        }
        if (DIVDEN) val = val / (den[(long)zh * sDh + (long)zl * sDl + gm0 + i] + 1e-6f);
        if (RESID) val += resid[cbase + (long)(gm0 + i) * ldc + gn];
        if (ACCUM) val += ((const float*)Cv)[cbase + (long)(gm0 + i) * ldc + gn];
        v4[i] = val;
      }
      if (OUTMODE == 0) {
        u16* C = (u16*)Cv;
        #pragma unroll
        for (int i = 0; i < 4; ++i) C[cbase + (long)(gm0 + i) * ldc + gn] = f2b(v4[i]);
      } else if (OUTMODE == 1) {
        float* C = (float*)Cv;
        #pragma unroll
        for (int i = 0; i < 4; ++i) C[cbase + (long)(gm0 + i) * ldc + gn] = v4[i];
      } else {
        // transposed attention write: gm = b*2048+s (s%4==0), gn = h*128+d
        u16* C = (u16*)Cv;
        const int b = gm0 >> 11, s = gm0 & 2047;
        const int h = gn >> 7,  d = gn & 127;
        u16x4 p;
        p[0] = f2b(v4[0]); p[1] = f2b(v4[1]); p[2] = f2b(v4[2]); p[3] = f2b(v4[3]);
        *(u16x4*)(C + (long)((b * 16 + h) * 128 + d) * 2048 + s) = p;
      }
    }
  }
}

// ---------------------------------------------------------------------------
extern "C" void kernel_launch(void* const* d_in, const int* in_sizes, int n_in,
                              void* d_out, int out_size, void* d_ws, size_t ws_size,
                              hipStream_t stream) {
  const float* x   = (const float*)d_in[0];
  const float* Wq  = (const float*)d_in[1];
  const float* bq  = (const float*)d_in[2];
  const float* Wk  = (const float*)d_in[3];
  const float* bk  = (const float*)d_in[4];
  const float* Wv  = (const float*)d_in[5];
  const float* bv  = (const float*)d_in[6];
  const float* Wo  = (const float*)d_in[7];
  const float* bo  = (const float*)d_in[8];
  const float* g1  = (const float*)d_in[9];
  const float* be1 = (const float*)d_in[10];
  const float* g2  = (const float*)d_in[11];
  const float* be2 = (const float*)d_in[12];
  const float* W1  = (const float*)d_in[13];
  const float* b1  = (const float*)d_in[14];
  const float* W2  = (const float*)d_in[15];
  const float* b2  = (const float*)d_in[16];
  const float* W3  = (const float*)d_in[17];
  const float* b3  = (const float*)d_in[18];
  const float* W4  = (const float*)d_in[19];
  const float* b4  = (const float*)d_in[20];
  float* xout = (float*)d_out;
  char* ws = (char*)d_ws;

  // workspace layout (bytes); total ~181 MB
  constexpr long DD2 = 2048L * 2048 * 2;          // DxD bf16
  constexpr size_t oWqT = 0;
  constexpr size_t oWkT = oWqT + DD2;
  constexpr size_t oWvT = oWkT + DD2;
  constexpr size_t oWoT = oWvT + DD2;
  constexpr size_t oW1T = oWoT + DD2;             // 256x2048 bf16
  constexpr size_t oW2T = oW1T + 256L * 2048 * 2; // 8192x256 bf16
  constexpr size_t oW3T = oW2T + 8192L * 256 * 2; // 256x8192 bf16
  constexpr size_t oW4T = oW3T + 256L * 8192 * 2; // 2048x256 bf16
  constexpr size_t oH1  = oW4T + 2048L * 256 * 2; // 8192x2048 bf16 (h1/attnN/t1)
  constexpr size_t oQ   = oH1 + 8192L * 2048 * 2; // q / h2
  constexpr size_t oKT  = oQ  + 8192L * 2048 * 2; // kT / t2chunk(+t3b)
  constexpr size_t oVT  = oKT + 8192L * 2048 * 2; // vT / t3(f32)
  constexpr size_t oKVT = oVT + 8192L * 2048 * 2; // 64x128x128 bf16
  constexpr size_t oKS  = oKVT + 64L * 128 * 128 * 2;
  constexpr size_t oDEN = oKS + 64L * 128 * 4;

  u16* WqT = (u16*)(ws + oWqT);
  u16* WkT = (u16*)(ws + oWkT);
  u16* WvT = (u16*)(ws + oWvT);
  u16* WoT = (u16*)(ws + oWoT);
  u16* W1T = (u16*)(ws + oW1T);
  u16* W2T = (u16*)(ws + oW2T);
  u16* W3T = (u16*)(ws + oW3T);
  u16* W4T = (u16*)(ws + oW4T);
  u16* H1   = (u16*)(ws + oH1);   // also attnN, t1
  u16* Qb   = (u16*)(ws + oQ);    // also h2
  u16* KT   = (u16*)(ws + oKT);   // also t2chunk
  u16* VT   = (u16*)(ws + oVT);
  float* T3f = (float*)(ws + oVT);
  u16* KVT = (u16*)(ws + oKVT);
  float* KS  = (float*)(ws + oKS);
  float* DEN = (float*)(ws + oDEN);
  u16* T1  = H1;
  u16* H2  = Qb;
  u16* T2C = KT;
  u16* T3B = (u16*)(ws + oKT + 8192L * 1024 * 2);

  const dim3 tb32(32, 8);
  // weights -> bf16 transposed (K-major for Bt operand)
  tpose_f32_bf16_kernel<<<dim3(64, 64), tb32, 0, stream>>>(Wq, WqT, 2048, 2048);
  tpose_f32_bf16_kernel<<<dim3(64, 64), tb32, 0, stream>>>(Wk, WkT, 2048, 2048);
  tpose_f32_bf16_kernel<<<dim3(64, 64), tb32, 0, stream>>>(Wv, WvT, 2048, 2048);
  tpose_f32_bf16_kernel<<<dim3(64, 64), tb32, 0, stream>>>(Wo, WoT, 2048, 2048);
  tpose_f32_bf16_kernel<<<dim3(8, 64),  tb32, 0, stream>>>(W1, W1T, 2048, 256);
  tpose_f32_bf16_kernel<<<dim3(256, 8), tb32, 0, stream>>>(W2, W2T, 256, 8192);
  tpose_f32_bf16_kernel<<<dim3(8, 256), tb32, 0, stream>>>(W3, W3T, 8192, 256);
  tpose_f32_bf16_kernel<<<dim3(64, 8),  tb32, 0, stream>>>(W4, W4T, 256, 2048);

  // h1 = LN1(x)
  ln_bf16_kernel<<<8192, 256, 0, stream>>>(x, g1, be1, H1);

  // q = elu(h1@Wq + bq)+1 ; k (transposed out) ; v (transposed out)
  btgemm_kernel<1, 0, 0, 0, 0><<<dim3(64, 16, 1), 256, 0, stream>>>(
      H1, WqT, Qb, bq, nullptr, nullptr, 8192, 2048, 2048, 2048, 2048, 2048, 1,
      0, 0, 0, 0, 0, 0, 0, 0);
  btgemm_kernel<1, 2, 0, 0, 0><<<dim3(64, 16, 1), 256, 0, stream>>>(
      H1, WkT, KT, bk, nullptr, nullptr, 8192, 2048, 2048, 2048, 2048, 2048, 1,
      0, 0, 0, 0, 0, 0, 0, 0);
  btgemm_kernel<0, 2, 0, 0, 0><<<dim3(64, 16, 1), 256, 0, stream>>>(
      H1, WvT, VT, bv, nullptr, nullptr, 8192, 2048, 2048, 2048, 2048, 2048, 1,
      0, 0, 0, 0, 0, 0, 0, 0);

  // ksum over S (from kT rows), den = q . ksum
  ksum_kernel<<<2048, 256, 0, stream>>>(KT, KS);
  den_kernel<<<8192, 256, 0, stream>>>(Qb, KS, DEN);

  // kvT[z][e][d] = sum_s v[s][e] k[s][d]   (z = b*16+h)
  btgemm_kernel<0, 0, 0, 0, 0><<<dim3(1, 1, 64), 256, 0, stream>>>(
      VT, KT, KVT, nullptr, nullptr, nullptr, 128, 128, 2048, 2048, 2048, 128, 1,
      262144, 0, 262144, 0, 16384, 0, 0, 0);

  // num = q @ kvT ; normalize by den -> attnN (bf16, (B,S,D) layout, reuses H1)
  btgemm_kernel<0, 0, 0, 0, 1><<<dim3(16, 1, 64), 256, 0, stream>>>(
      Qb, KVT, H1, nullptr, nullptr, DEN, 2048, 128, 128, 2048, 128, 2048, 16,
      4194304, 128, 262144, 16384, 4194304, 128, 32768, 2048);

  // x2 = x + attnN@Wo + bo  -> d_out (f32)
  btgemm_kernel<0, 1, 1, 0, 0><<<dim3(64, 16, 1), 256, 0, stream>>>(
      H1, WoT, xout, bo, x, nullptr, 8192, 2048, 2048, 2048, 2048, 2048, 1,
      0, 0, 0, 0, 0, 0, 0, 0);

  // h2 = LN2(x2)
  ln_bf16_kernel<<<8192, 256, 0, stream>>>(xout, g2, be2, H2);

  // t1 = h2@W1 + b1 (bf16)
  btgemm_kernel<0, 0, 0, 0, 0><<<dim3(64, 2, 1), 256, 0, stream>>>(
      H2, W1T, T1, b1, nullptr, nullptr, 8192, 256, 2048, 2048, 2048, 256, 1,
      0, 0, 0, 0, 0, 0, 0, 0);

  // FFN middle in 8 HID-chunks of 1024: t2c = gelu(t1@W2c + b2c); t3 (+)= t2c@W3c
  for (int c = 0; c < 8; ++c) {
    btgemm_kernel<2, 0, 0, 0, 0><<<dim3(64, 8, 1), 256, 0, stream>>>(
        T1, W2T + (long)c * 1024 * 256, T2C, b2 + c * 1024, nullptr, nullptr,
        8192, 1024, 256, 256, 256, 1024, 1, 0, 0, 0, 0, 0, 0, 0, 0);
    if (c == 0)
      btgemm_kernel<0, 1, 0, 0, 0><<<dim3(64, 2, 1), 256, 0, stream>>>(
          T2C, W3T + 0, T3f, b3, nullptr, nullptr,
          8192, 256, 1024, 1024, 8192, 256, 1, 0, 0, 0, 0, 0, 0, 0, 0);
    else
      btgemm_kernel<0, 1, 0, 1, 0><<<dim3(64, 2, 1), 256, 0, stream>>>(
          T2C, W3T + (long)c * 1024, T3f, nullptr, nullptr, nullptr,
          8192, 256, 1024, 1024, 8192, 256, 1, 0, 0, 0, 0, 0, 0, 0, 0);
  }

  // t3 -> bf16
  cvt_f32_bf16_kernel<<<2048, 256, 0, stream>>>(T3f, T3B, 8192L * 256);

  // out = x2 + t3@W4 + b4   (resid = d_out itself)
  btgemm_kernel<0, 1, 1, 0, 0><<<dim3(64, 16, 1), 256, 0, stream>>>(
      T3B, W4T, xout, b4, xout, nullptr, 8192, 2048, 256, 256, 256, 2048, 1,
      0, 0, 0, 0, 0, 0, 0, 0);
}

// Round 2
// 1311.887 us; speedup vs baseline: 1.0152x; 1.0152x over previous
//
#include <hip/hip_runtime.h>
#include <hip/hip_bf16.h>
#include <cstdint>

typedef float     f32x4  __attribute__((ext_vector_type(4)));
typedef __bf16    bf16x8 __attribute__((ext_vector_type(8)));
typedef unsigned short u16x4 __attribute__((ext_vector_type(4)));
typedef unsigned short u16x8 __attribute__((ext_vector_type(8)));
typedef unsigned short u16;

#define DI __device__ __forceinline__

DI float b2f(u16 u) { union { unsigned int i; float f; } x; x.i = ((unsigned int)u) << 16; return x.f; }
DI u16 f2b(float f) {
  union { float f; unsigned int i; } x; x.f = f;
  return (u16)((x.i + 0x7FFFu + ((x.i >> 16) & 1u)) >> 16);   // RNE
}

// direct global->LDS async copy, 16B per lane (m97 structure)
DI void gload16(const void* g, void* l) {
  __builtin_amdgcn_global_load_lds(
      (const __attribute__((address_space(1))) unsigned int*)g,
      (__attribute__((address_space(3))) unsigned int*)l, 16, 0, 0);
}

// ---------------------------------------------------------------------------
// Transpose + fp32->bf16 convert: src (R x C) f32 row-major -> dst (C x R) bf16
// ---------------------------------------------------------------------------
__global__ __launch_bounds__(256) void tpose_f32_bf16_kernel(
    const float* __restrict__ src, u16* __restrict__ dst, int R, int C)
{
  __shared__ float tile[32][33];
  const int c0 = blockIdx.x * 32, r0 = blockIdx.y * 32;
  const int tx = threadIdx.x, ty = threadIdx.y;
  #pragma unroll
  for (int i = 0; i < 4; ++i)
    tile[ty + i * 8][tx] = src[(long)(r0 + ty + i * 8) * C + c0 + tx];
  __syncthreads();
  #pragma unroll
  for (int i = 0; i < 4; ++i)
    dst[(long)(c0 + ty + i * 8) * R + r0 + tx] = f2b(tile[tx][ty + i * 8]);
}

// ---------------------------------------------------------------------------
// LayerNorm (row of 2048) fp32 -> bf16.  grid = B*S rows, 256 threads.
// ---------------------------------------------------------------------------
__global__ __launch_bounds__(256) void ln_bf16_kernel(
    const float* __restrict__ x, const float* __restrict__ gamma,
    const float* __restrict__ beta, u16* __restrict__ out)
{
  const long row = blockIdx.x;
  const float* xr = x + row * 2048;
  const int tid = threadIdx.x;
  float4 a = *(const float4*)(xr + tid * 8);
  float4 b = *(const float4*)(xr + tid * 8 + 4);
  float s  = a.x + a.y + a.z + a.w + b.x + b.y + b.z + b.w;
  float ss = a.x*a.x + a.y*a.y + a.z*a.z + a.w*a.w
           + b.x*b.x + b.y*b.y + b.z*b.z + b.w*b.w;
  #pragma unroll
  for (int off = 1; off < 64; off <<= 1) { s += __shfl_xor(s, off); ss += __shfl_xor(ss, off); }
  __shared__ float red[8];
  if ((tid & 63) == 0) { red[tid >> 6] = s; red[4 + (tid >> 6)] = ss; }
  __syncthreads();
  s  = red[0] + red[1] + red[2] + red[3];
  ss = red[4] + red[5] + red[6] + red[7];
  const float mu = s * (1.0f / 2048.0f);
  const float rs = rsqrtf(ss * (1.0f / 2048.0f) - mu * mu + 1e-5f);
  const float v[8] = {a.x, a.y, a.z, a.w, b.x, b.y, b.z, b.w};
  u16x8 o;
  #pragma unroll
  for (int j = 0; j < 8; ++j) {
    const int col = tid * 8 + j;
    o[j] = f2b((v[j] - mu) * rs * gamma[col] + beta[col]);
  }
  *(u16x8*)(out + row * 2048 + tid * 8) = o;
}

// ---------------------------------------------------------------------------
// ksum[d_row] = sum_s kT[d_row][s]
// ---------------------------------------------------------------------------
__global__ __launch_bounds__(256) void ksum_kernel(
    const u16* __restrict__ kT, float* __restrict__ ksum)
{
  const int gw = blockIdx.x * 4 + (threadIdx.x >> 6);
  const int lane = threadIdx.x & 63;
  const u16* r = kT + (long)gw * 2048;
  float s = 0.f;
  #pragma unroll
  for (int j = 0; j < 4; ++j) {
    u16x8 v = *(const u16x8*)(r + j * 512 + lane * 8);
    #pragma unroll
    for (int e = 0; e < 8; ++e) s += b2f(v[e]);
  }
  #pragma unroll
  for (int off = 1; off < 64; off <<= 1) s += __shfl_xor(s, off);
  if (lane == 0) ksum[gw] = s;
}

// ---------------------------------------------------------------------------
// den[b][h][s] = dot(q[b][s][h*128:], ksum[b][h][:])
// ---------------------------------------------------------------------------
__global__ __launch_bounds__(256) void den_kernel(
    const u16* __restrict__ q, const float* __restrict__ ksum, float* __restrict__ den)
{
  const long m = blockIdx.x;            // b*2048 + s
  const int tid = threadIdx.x;
  const int b = (int)(m >> 11);
  const int h = tid >> 4;
  const int dl = (tid & 15) * 8;
  const u16* qr = q + m * 2048 + h * 128 + dl;
  const float* ks = ksum + ((long)b * 16 + h) * 128 + dl;
  u16x8 v = *(const u16x8*)qr;
  float s = 0.f;
  #pragma unroll
  for (int e = 0; e < 8; ++e) s += b2f(v[e]) * ks[e];
  #pragma unroll
  for (int off = 1; off < 16; off <<= 1) s += __shfl_xor(s, off);
  if ((tid & 15) == 0) den[((long)b * 16 + h) * 2048 + (m & 2047)] = s;
}

// ---------------------------------------------------------------------------
// fp32 -> bf16 elementwise
// ---------------------------------------------------------------------------
__global__ __launch_bounds__(256) void cvt_f32_bf16_kernel(
    const float* __restrict__ src, u16* __restrict__ dst, long n)
{
  long i = ((long)blockIdx.x * 256 + threadIdx.x) * 4;
  if (i >= n) return;
  float4 v = *(const float4*)(src + i);
  u16x4 o; o[0] = f2b(v.x); o[1] = f2b(v.y); o[2] = f2b(v.z); o[3] = f2b(v.w);
  *(u16x4*)(dst + i) = o;
}

// ---------------------------------------------------------------------------
// kv split-K reduce: out_bf16[i] = sum_{p<8} partial[p][i], i < 64*128*128
// ---------------------------------------------------------------------------
__global__ __launch_bounds__(256) void kvreduce_kernel(
    const float* __restrict__ p, u16* __restrict__ out)
{
  long i = ((long)blockIdx.x * 256 + threadIdx.x) * 4;
  float4 s = *(const float4*)(p + i);
  #pragma unroll
  for (int j = 1; j < 8; ++j) {
    float4 v = *(const float4*)(p + (long)j * 1048576 + i);
    s.x += v.x; s.y += v.y; s.z += v.z; s.w += v.w;
  }
  u16x4 o; o[0] = f2b(s.x); o[1] = f2b(s.y); o[2] = f2b(s.z); o[3] = f2b(s.w);
  *(u16x4*)(out + i) = o;
}

// ---------------------------------------------------------------------------
// bt-GEMM (m97 structure): C[m][n] = sum_k A[m][k]*Bt[n][k], bf16 in, fp32 acc.
// 128x128 tile, BK=64, 256 thr (4 waves 2x2, each 64x64 = 4x4 MFMA frags).
// Staging via global_load_lds width16 into LINEAR LDS (no swizzle: rule #21).
// ACT: 0 none, 1 elu+1, 2 tanh-gelu. OUTMODE: 0 bf16, 1 f32, 2 bf16-transposed.
// RESID: +resid[f32]. ACCUM: +C_old[f32]. DIVDEN: /(den[row]+eps).
// ---------------------------------------------------------------------------
template<int ACT, int OUTMODE, int RESID, int ACCUM, int DIVDEN>
__global__ __launch_bounds__(256) void btgemm_kernel(
    const u16* __restrict__ A, const u16* __restrict__ Bt, void* Cv,
    const float* __restrict__ bias, const float* resid, const float* __restrict__ den,
    int M, int N, int K, int lda, int ldb, int ldc, int ZMOD,
    long sAh, long sAl, long sBh, long sBl, long sCh, long sCl, long sDh, long sDl)
{
  __shared__ char lds[32768];
  char* As = lds;
  char* Bs = lds + 16384;
  const int tid = threadIdx.x;
  const int wave = tid >> 6, lane = tid & 63;
  const int lr = lane & 15, lk = lane >> 4;
  const int wr = wave >> 1, wc = wave & 1;
  const int z = blockIdx.z;
  const int zh = z / ZMOD, zl = z % ZMOD;
  const char* Ab = (const char*)(A + zh * sAh + zl * sAl + (long)blockIdx.x * 128 * lda);
  const char* Bb = (const char*)(Bt + zh * sBh + zl * sBl + (long)blockIdx.y * 128 * ldb);
  const long ldaB = (long)lda * 2, ldbB = (long)ldb * 2;

  f32x4 acc[4][4] = {};

  for (int k0 = 0; k0 < K; k0 += 64) {
    // stage A,B tiles (128 rows x 64 cols bf16 = 16384B each = 1024 x 16B chunks)
    #pragma unroll
    for (int i = 0; i < 4; ++i) {
      const int c = i * 256 + tid;          // chunk 0..1023
      const int row = c >> 3;
      const int cb = (c & 7) * 16;          // byte col in 128B row
      gload16(Ab + (long)row * ldaB + k0 * 2 + cb, As + c * 16);
      gload16(Bb + (long)row * ldbB + k0 * 2 + cb, Bs + c * 16);
    }
    __syncthreads();
    #pragma unroll
    for (int kk = 0; kk < 64; kk += 32) {
      bf16x8 af[4], bf[4];
      #pragma unroll
      for (int m = 0; m < 4; ++m)
        af[m] = *(const bf16x8*)(As + (wr * 64 + m * 16 + lr) * 128 + (kk + lk * 8) * 2);
      #pragma unroll
      for (int n = 0; n < 4; ++n)
        bf[n] = *(const bf16x8*)(Bs + (wc * 64 + n * 16 + lr) * 128 + (kk + lk * 8) * 2);
      #pragma unroll
      for (int m = 0; m < 4; ++m)
        #pragma unroll
        for (int n = 0; n < 4; ++n)
          acc[m][n] = __builtin_amdgcn_mfma_f32_16x16x32_bf16(af[m], bf[n], acc[m][n], 0, 0, 0);
    }
    __syncthreads();
  }

  const long cbase = (long)zh * sCh + (long)zl * sCl;
  #pragma unroll
  for (int m = 0; m < 4; ++m) {
    #pragma unroll
    for (int n = 0; n < 4; ++n) {
      const int gm0 = blockIdx.x * 128 + wr * 64 + m * 16 + lk * 4;
      const int gn  = blockIdx.y * 128 + wc * 64 + n * 16 + lr;
      float v4[4];
      #pragma unroll
      for (int i = 0; i < 4; ++i) {
        float val = acc[m][n][i];
        if (bias) val += bias[gn];
        if (ACT == 1) val = (val > 0.f) ? (val + 1.f) : __builtin_exp2f(val * 1.4426950408889634f);
        if (ACT == 2) {
          const float u = val;
          const float y = 0.7978845608028654f * (u + 0.044715f * u * u * u);
          const float t = 1.0f - 2.0f / (__builtin_exp2f(y * 2.885390081777927f) + 1.0f);
          val = 0.5f * u * (1.0f + t);
        }
        if (DIVDEN) val = val / (den[(long)zh * sDh + (long)zl * sDl + gm0 + i] + 1e-6f);
        if (RESID) val += resid[cbase + (long)(gm0 + i) * ldc + gn];
        if (ACCUM) val += ((const float*)Cv)[cbase + (long)(gm0 + i) * ldc + gn];
        v4[i] = val;
      }
      if (OUTMODE == 0) {
        u16* C = (u16*)Cv;
        #pragma unroll
        for (int i = 0; i < 4; ++i) C[cbase + (long)(gm0 + i) * ldc + gn] = f2b(v4[i]);
      } else if (OUTMODE == 1) {
        float* C = (float*)Cv;
        #pragma unroll
        for (int i = 0; i < 4; ++i) C[cbase + (long)(gm0 + i) * ldc + gn] = v4[i];
      } else {
        // transposed attention write: gm = b*2048+s (s%4==0), gn = h*128+d
        u16* C = (u16*)Cv;
        const int b = gm0 >> 11, s = gm0 & 2047;
        const int h = gn >> 7,  d = gn & 127;
        u16x4 p;
        p[0] = f2b(v4[0]); p[1] = f2b(v4[1]); p[2] = f2b(v4[2]); p[3] = f2b(v4[3]);
        *(u16x4*)(C + (long)((b * 16 + h) * 128 + d) * 2048 + s) = p;
      }
    }
  }
}

// ---------------------------------------------------------------------------
extern "C" void kernel_launch(void* const* d_in, const int* in_sizes, int n_in,
                              void* d_out, int out_size, void* d_ws, size_t ws_size,
                              hipStream_t stream) {
  const float* x   = (const float*)d_in[0];
  const float* Wq  = (const float*)d_in[1];
  const float* bq  = (const float*)d_in[2];
  const float* Wk  = (const float*)d_in[3];
  const float* bk  = (const float*)d_in[4];
  const float* Wv  = (const float*)d_in[5];
  const float* bv  = (const float*)d_in[6];
  const float* Wo  = (const float*)d_in[7];
  const float* bo  = (const float*)d_in[8];
  const float* g1  = (const float*)d_in[9];
  const float* be1 = (const float*)d_in[10];
  const float* g2  = (const float*)d_in[11];
  const float* be2 = (const float*)d_in[12];
  const float* W1  = (const float*)d_in[13];
  const float* b1  = (const float*)d_in[14];
  const float* W2  = (const float*)d_in[15];
  const float* b2  = (const float*)d_in[16];
  const float* W3  = (const float*)d_in[17];
  const float* b3  = (const float*)d_in[18];
  const float* W4  = (const float*)d_in[19];
  const float* b4  = (const float*)d_in[20];
  float* xout = (float*)d_out;
  char* ws = (char*)d_ws;

  // workspace layout (bytes); total ~181 MB
  constexpr long DD2 = 2048L * 2048 * 2;          // DxD bf16
  constexpr size_t oWqT = 0;
  constexpr size_t oWkT = oWqT + DD2;
  constexpr size_t oWvT = oWkT + DD2;
  constexpr size_t oWoT = oWvT + DD2;
  constexpr size_t oW1T = oWoT + DD2;             // 256x2048 bf16
  constexpr size_t oW2T = oW1T + 256L * 2048 * 2; // 8192x256 bf16
  constexpr size_t oW3T = oW2T + 8192L * 256 * 2; // 256x8192 bf16
  constexpr size_t oW4T = oW3T + 256L * 8192 * 2; // 2048x256 bf16
  constexpr size_t oH1  = oW4T + 2048L * 256 * 2; // 8192x2048 bf16 (h1/kvpart/attnN/t1)
  constexpr size_t oQ   = oH1 + 8192L * 2048 * 2; // q / h2
  constexpr size_t oKT  = oQ  + 8192L * 2048 * 2; // kT / t2chunk
  constexpr size_t oVT  = oKT + 8192L * 2048 * 2; // vT / t3(f32) / t3(bf16)
  constexpr size_t oKVT = oVT + 8192L * 2048 * 2; // 64x128x128 bf16
  constexpr size_t oKS  = oKVT + 64L * 128 * 128 * 2;
  constexpr size_t oDEN = oKS + 64L * 128 * 4;

  u16* WqT = (u16*)(ws + oWqT);
  u16* WkT = (u16*)(ws + oWkT);
  u16* WvT = (u16*)(ws + oWvT);
  u16* WoT = (u16*)(ws + oWoT);
  u16* W1T = (u16*)(ws + oW1T);
  u16* W2T = (u16*)(ws + oW2T);
  u16* W3T = (u16*)(ws + oW3T);
  u16* W4T = (u16*)(ws + oW4T);
  u16* H1   = (u16*)(ws + oH1);    // h1; then kv partials (f32); then attnN
  float* KVP = (float*)(ws + oH1); // kv split-K partials: [8][64][128][128] f32
  u16* Qb   = (u16*)(ws + oQ);     // q; then h2
  u16* KT   = (u16*)(ws + oKT);    // kT; then t2 chunk
  u16* VT   = (u16*)(ws + oVT);    // vT; then t3
  float* T3f = (float*)(ws + oVT);
  u16* KVT = (u16*)(ws + oKVT);
  float* KS  = (float*)(ws + oKS);
  float* DEN = (float*)(ws + oDEN);
  u16* T1  = H1;
  u16* H2  = Qb;
  u16* T2C = KT;
  u16* T3B = (u16*)(ws + oVT + 16L * 1024 * 1024);

  const dim3 tb32(32, 8);
  // weights -> bf16 transposed (K-major for Bt operand)
  tpose_f32_bf16_kernel<<<dim3(64, 64), tb32, 0, stream>>>(Wq, WqT, 2048, 2048);
  tpose_f32_bf16_kernel<<<dim3(64, 64), tb32, 0, stream>>>(Wk, WkT, 2048, 2048);
  tpose_f32_bf16_kernel<<<dim3(64, 64), tb32, 0, stream>>>(Wv, WvT, 2048, 2048);
  tpose_f32_bf16_kernel<<<dim3(64, 64), tb32, 0, stream>>>(Wo, WoT, 2048, 2048);
  tpose_f32_bf16_kernel<<<dim3(8, 64),  tb32, 0, stream>>>(W1, W1T, 2048, 256);
  tpose_f32_bf16_kernel<<<dim3(256, 8), tb32, 0, stream>>>(W2, W2T, 256, 8192);
  tpose_f32_bf16_kernel<<<dim3(8, 256), tb32, 0, stream>>>(W3, W3T, 8192, 256);
  tpose_f32_bf16_kernel<<<dim3(64, 8),  tb32, 0, stream>>>(W4, W4T, 256, 2048);

  // h1 = LN1(x)
  ln_bf16_kernel<<<8192, 256, 0, stream>>>(x, g1, be1, H1);

  // q = elu(h1@Wq+bq)+1 ; k,v transposed-out (B,H,HD,S)
  btgemm_kernel<1, 0, 0, 0, 0><<<dim3(64, 16, 1), 256, 0, stream>>>(
      H1, WqT, Qb, bq, nullptr, nullptr, 8192, 2048, 2048, 2048, 2048, 2048, 1,
      0, 0, 0, 0, 0, 0, 0, 0);
  btgemm_kernel<1, 2, 0, 0, 0><<<dim3(64, 16, 1), 256, 0, stream>>>(
      H1, WkT, KT, bk, nullptr, nullptr, 8192, 2048, 2048, 2048, 2048, 2048, 1,
      0, 0, 0, 0, 0, 0, 0, 0);
  btgemm_kernel<0, 2, 0, 0, 0><<<dim3(64, 16, 1), 256, 0, stream>>>(
      H1, WvT, VT, bv, nullptr, nullptr, 8192, 2048, 2048, 2048, 2048, 2048, 1,
      0, 0, 0, 0, 0, 0, 0, 0);

  // ksum over S, den = q.ksum
  ksum_kernel<<<2048, 256, 0, stream>>>(KT, KS);
  den_kernel<<<8192, 256, 0, stream>>>(Qb, KS, DEN);

  // kv split-K: partial[p][z][e][d] = sum_{s in chunk p} v[s][e] k[s][d]
  // z = zz*8+p: zh=zz (head), zl=p (K-chunk)
  btgemm_kernel<0, 1, 0, 0, 0><<<dim3(1, 1, 512), 256, 0, stream>>>(
      VT, KT, KVP, nullptr, nullptr, nullptr, 128, 128, 256, 2048, 2048, 128, 8,
      262144, 256, 262144, 256, 16384, 1048576, 0, 0);
  kvreduce_kernel<<<1024, 256, 0, stream>>>(KVP, KVT);

  // num = q @ kvT ; /(den+eps) -> attnN (bf16, (B,S,D), reuses H1)
  btgemm_kernel<0, 0, 0, 0, 1><<<dim3(16, 1, 64), 256, 0, stream>>>(
      Qb, KVT, H1, nullptr, nullptr, DEN, 2048, 128, 128, 2048, 128, 2048, 16,
      4194304, 128, 262144, 16384, 4194304, 128, 32768, 2048);

  // x2 = x + attnN@Wo + bo -> d_out (f32)
  btgemm_kernel<0, 1, 1, 0, 0><<<dim3(64, 16, 1), 256, 0, stream>>>(
      H1, WoT, xout, bo, x, nullptr, 8192, 2048, 2048, 2048, 2048, 2048, 1,
      0, 0, 0, 0, 0, 0, 0, 0);

  // h2 = LN2(x2)
  ln_bf16_kernel<<<8192, 256, 0, stream>>>(xout, g2, be2, H2);

  // t1 = h2@W1 + b1 (bf16)
  btgemm_kernel<0, 0, 0, 0, 0><<<dim3(64, 2, 1), 256, 0, stream>>>(
      H2, W1T, T1, b1, nullptr, nullptr, 8192, 256, 2048, 2048, 2048, 256, 1,
      0, 0, 0, 0, 0, 0, 0, 0);

  // FFN middle in 4 HID-chunks of 2048: t2c = gelu(t1@W2c+b2c); t3 (+)= t2c@W3c
  for (int c = 0; c < 4; ++c) {
    btgemm_kernel<2, 0, 0, 0, 0><<<dim3(64, 16, 1), 256, 0, stream>>>(
        T1, W2T + (long)c * 2048 * 256, T2C, b2 + c * 2048, nullptr, nullptr,
        8192, 2048, 256, 256, 256, 2048, 1, 0, 0, 0, 0, 0, 0, 0, 0);
    if (c == 0)
      btgemm_kernel<0, 1, 0, 0, 0><<<dim3(64, 2, 1), 256, 0, stream>>>(
          T2C, W3T + 0, T3f, b3, nullptr, nullptr,
          8192, 256, 2048, 2048, 8192, 256, 1, 0, 0, 0, 0, 0, 0, 0, 0);
    else
      btgemm_kernel<0, 1, 0, 1, 0><<<dim3(64, 2, 1), 256, 0, stream>>>(
          T2C, W3T + (long)c * 2048, T3f, nullptr, nullptr, nullptr,
          8192, 256, 2048, 2048, 8192, 256, 1, 0, 0, 0, 0, 0, 0, 0, 0);
  }

  // t3 -> bf16
  cvt_f32_bf16_kernel<<<2048, 256, 0, stream>>>(T3f, T3B, 8192L * 256);

  // out = x2 + t3@W4 + b4   (resid = d_out itself)
  btgemm_kernel<0, 1, 1, 0, 0><<<dim3(64, 16, 1), 256, 0, stream>>>(
      T3B, W4T, xout, b4, xout, nullptr, 8192, 2048, 256, 256, 256, 2048, 1,
      0, 0, 0, 0, 0, 0, 0, 0);
}

// Round 3
// 1149.686 us; speedup vs baseline: 1.1584x; 1.1411x over previous
//
#include <hip/hip_runtime.h>
#include <hip/hip_bf16.h>
#include <cstdint>

typedef float     f32x4  __attribute__((ext_vector_type(4)));
typedef __bf16    bf16x8 __attribute__((ext_vector_type(8)));
typedef unsigned short u16x4 __attribute__((ext_vector_type(4)));
typedef unsigned short u16x8 __attribute__((ext_vector_type(8)));
typedef unsigned short u16;

#define DI __device__ __forceinline__

DI float b2f(u16 u) { union { unsigned int i; float f; } x; x.i = ((unsigned int)u) << 16; return x.f; }
DI u16 f2b(float f) {
  union { float f; unsigned int i; } x; x.f = f;
  return (u16)((x.i + 0x7FFFu + ((x.i >> 16) & 1u)) >> 16);   // RNE
}

// direct global->LDS async copy, 16B per lane (m97 structure)
DI void gload16(const void* g, void* l) {
  __builtin_amdgcn_global_load_lds(
      (const __attribute__((address_space(1))) unsigned int*)g,
      (__attribute__((address_space(3))) unsigned int*)l, 16, 0, 0);
}

// ---------------------------------------------------------------------------
// Transpose + fp32->bf16 convert: src (R x C) f32 row-major -> dst (C x R) bf16
// ---------------------------------------------------------------------------
__global__ __launch_bounds__(256) void tpose_f32_bf16_kernel(
    const float* __restrict__ src, u16* __restrict__ dst, int R, int C)
{
  __shared__ float tile[32][33];
  const int c0 = blockIdx.x * 32, r0 = blockIdx.y * 32;
  const int tx = threadIdx.x, ty = threadIdx.y;
  #pragma unroll
  for (int i = 0; i < 4; ++i)
    tile[ty + i * 8][tx] = src[(long)(r0 + ty + i * 8) * C + c0 + tx];
  __syncthreads();
  #pragma unroll
  for (int i = 0; i < 4; ++i)
    dst[(long)(c0 + ty + i * 8) * R + r0 + tx] = f2b(tile[tx][ty + i * 8]);
}

// ---------------------------------------------------------------------------
// LayerNorm (row of 2048) fp32 -> bf16.
// ---------------------------------------------------------------------------
__global__ __launch_bounds__(256) void ln_bf16_kernel(
    const float* __restrict__ x, const float* __restrict__ gamma,
    const float* __restrict__ beta, u16* __restrict__ out)
{
  const long row = blockIdx.x;
  const float* xr = x + row * 2048;
  const int tid = threadIdx.x;
  float4 a = *(const float4*)(xr + tid * 8);
  float4 b = *(const float4*)(xr + tid * 8 + 4);
  float s  = a.x + a.y + a.z + a.w + b.x + b.y + b.z + b.w;
  float ss = a.x*a.x + a.y*a.y + a.z*a.z + a.w*a.w
           + b.x*b.x + b.y*b.y + b.z*b.z + b.w*b.w;
  #pragma unroll
  for (int off = 1; off < 64; off <<= 1) { s += __shfl_xor(s, off); ss += __shfl_xor(ss, off); }
  __shared__ float red[8];
  if ((tid & 63) == 0) { red[tid >> 6] = s; red[4 + (tid >> 6)] = ss; }
  __syncthreads();
  s  = red[0] + red[1] + red[2] + red[3];
  ss = red[4] + red[5] + red[6] + red[7];
  const float mu = s * (1.0f / 2048.0f);
  const float rs = rsqrtf(ss * (1.0f / 2048.0f) - mu * mu + 1e-5f);
  const float v[8] = {a.x, a.y, a.z, a.w, b.x, b.y, b.z, b.w};
  u16x8 o;
  #pragma unroll
  for (int j = 0; j < 8; ++j) {
    const int col = tid * 8 + j;
    o[j] = f2b((v[j] - mu) * rs * gamma[col] + beta[col]);
  }
  *(u16x8*)(out + row * 2048 + tid * 8) = o;
}

// ---------------------------------------------------------------------------
// ksum[d_row] = sum_s kT[d_row][s]
// ---------------------------------------------------------------------------
__global__ __launch_bounds__(256) void ksum_kernel(
    const u16* __restrict__ kT, float* __restrict__ ksum)
{
  const int gw = blockIdx.x * 4 + (threadIdx.x >> 6);
  const int lane = threadIdx.x & 63;
  const u16* r = kT + (long)gw * 2048;
  float s = 0.f;
  #pragma unroll
  for (int j = 0; j < 4; ++j) {
    u16x8 v = *(const u16x8*)(r + j * 512 + lane * 8);
    #pragma unroll
    for (int e = 0; e < 8; ++e) s += b2f(v[e]);
  }
  #pragma unroll
  for (int off = 1; off < 64; off <<= 1) s += __shfl_xor(s, off);
  if (lane == 0) ksum[gw] = s;
}

// ---------------------------------------------------------------------------
// den[b][h][s] = dot(q[b][s][h*128:], ksum[b][h][:])
// ---------------------------------------------------------------------------
__global__ __launch_bounds__(256) void den_kernel(
    const u16* __restrict__ q, const float* __restrict__ ksum, float* __restrict__ den)
{
  const long m = blockIdx.x;            // b*2048 + s
  const int tid = threadIdx.x;
  const int b = (int)(m >> 11);
  const int h = tid >> 4;
  const int dl = (tid & 15) * 8;
  const u16* qr = q + m * 2048 + h * 128 + dl;
  const float* ks = ksum + ((long)b * 16 + h) * 128 + dl;
  u16x8 v = *(const u16x8*)qr;
  float s = 0.f;
  #pragma unroll
  for (int e = 0; e < 8; ++e) s += b2f(v[e]) * ks[e];
  #pragma unroll
  for (int off = 1; off < 16; off <<= 1) s += __shfl_xor(s, off);
  if ((tid & 15) == 0) den[((long)b * 16 + h) * 2048 + (m & 2047)] = s;
}

// ---------------------------------------------------------------------------
// fp32 -> bf16 elementwise
// ---------------------------------------------------------------------------
__global__ __launch_bounds__(256) void cvt_f32_bf16_kernel(
    const float* __restrict__ src, u16* __restrict__ dst, long n)
{
  long i = ((long)blockIdx.x * 256 + threadIdx.x) * 4;
  if (i >= n) return;
  float4 v = *(const float4*)(src + i);
  u16x4 o; o[0] = f2b(v.x); o[1] = f2b(v.y); o[2] = f2b(v.z); o[3] = f2b(v.w);
  *(u16x4*)(dst + i) = o;
}

// ---------------------------------------------------------------------------
// kv split-K reduce: out_bf16[i] = sum_{p<8} partial[p][i]
// ---------------------------------------------------------------------------
__global__ __launch_bounds__(256) void kvreduce_kernel(
    const float* __restrict__ p, u16* __restrict__ out)
{
  long i = ((long)blockIdx.x * 256 + threadIdx.x) * 4;
  float4 s = *(const float4*)(p + i);
  #pragma unroll
  for (int j = 1; j < 8; ++j) {
    float4 v = *(const float4*)(p + (long)j * 1048576 + i);
    s.x += v.x; s.y += v.y; s.z += v.z; s.w += v.w;
  }
  u16x4 o; o[0] = f2b(s.x); o[1] = f2b(s.y); o[2] = f2b(s.z); o[3] = f2b(s.w);
  *(u16x4*)(out + i) = o;
}

// ---------------------------------------------------------------------------
// RANK split-K reduce: out[i] = sum_{p<NP} P[p][i] (+bias[col]) (+out_old)
// partial stride 2097152 f32 (= 8192x256). OUTF32: 1 f32, 0 bf16.
// ---------------------------------------------------------------------------
template<int NP, int OUTF32, int ACC>
__global__ __launch_bounds__(256) void rankreduce_kernel(
    const float* __restrict__ p, const float* __restrict__ bias, void* out)
{
  long i = ((long)blockIdx.x * 256 + threadIdx.x) * 4;
  float4 s = *(const float4*)(p + i);
  #pragma unroll
  for (int j = 1; j < NP; ++j) {
    float4 v = *(const float4*)(p + (long)j * 2097152 + i);
    s.x += v.x; s.y += v.y; s.z += v.z; s.w += v.w;
  }
  if (bias) {
    const int col = (int)(i & 255);
    s.x += bias[col]; s.y += bias[col + 1]; s.z += bias[col + 2]; s.w += bias[col + 3];
  }
  if (ACC) {
    float4 o = *(const float4*)((const float*)out + i);
    s.x += o.x; s.y += o.y; s.z += o.z; s.w += o.w;
  }
  if (OUTF32) {
    *(float4*)((float*)out + i) = s;
  } else {
    u16x4 o; o[0] = f2b(s.x); o[1] = f2b(s.y); o[2] = f2b(s.z); o[3] = f2b(s.w);
    *(u16x4*)((u16*)out + i) = o;
  }
}

// ---------------------------------------------------------------------------
// 256x256-tile bt-GEMM (2-phase, m230-V0 structure): C[m][n]=sum_k A[m][k]Bt[n][k]
// 512 thr = 8 waves (2Mx4N), per-wave 128x64 out (8x4 frags), BK=64, LDS 64KB.
// ACT: 0 none, 1 elu+1, 2 tanh-gelu. OUTMODE: 0 bf16, 1 f32, 2 bf16-transposed.
// RESID: +resid[f32].
// ---------------------------------------------------------------------------
template<int ACT, int OUTMODE, int RESID>
__global__ __launch_bounds__(512, 2) void btgemm256_kernel(
    const u16* __restrict__ A, const u16* __restrict__ Bt, void* Cv,
    const float* __restrict__ bias, const float* resid,
    int K, int lda, int ldb, int ldc)
{
  __shared__ char lds[65536];
  char* As = lds;                // 256 rows x 128B
  char* Bs = lds + 32768;
  const int tid = threadIdx.x;
  const int wave = tid >> 6, lane = tid & 63;
  const int lr = lane & 15, lk = lane >> 4;
  const int wr = wave >> 2, wc = wave & 3;
  const char* Ab = (const char*)(A + (long)blockIdx.x * 256 * lda);
  const char* Bb = (const char*)(Bt + (long)blockIdx.y * 256 * ldb);
  const long ldaB = (long)lda * 2, ldbB = (long)ldb * 2;

  f32x4 acc[8][4] = {};

  for (int k0 = 0; k0 < K; k0 += 64) {
    #pragma unroll
    for (int i = 0; i < 4; ++i) {
      const int c = i * 512 + tid;       // 16B chunk 0..2047
      const int row = c >> 3;
      const int cb = (c & 7) * 16;
      gload16(Ab + (long)row * ldaB + k0 * 2 + cb, As + c * 16);
      gload16(Bb + (long)row * ldbB + k0 * 2 + cb, Bs + c * 16);
    }
    __syncthreads();
    #pragma unroll
    for (int kk = 0; kk < 64; kk += 32) {
      bf16x8 af[8], bf[4];
      #pragma unroll
      for (int m = 0; m < 8; ++m)
        af[m] = *(const bf16x8*)(As + (wr * 128 + m * 16 + lr) * 128 + (kk + lk * 8) * 2);
      #pragma unroll
      for (int n = 0; n < 4; ++n)
        bf[n] = *(const bf16x8*)(Bs + (wc * 64 + n * 16 + lr) * 128 + (kk + lk * 8) * 2);
      #pragma unroll
      for (int m = 0; m < 8; ++m)
        #pragma unroll
        for (int n = 0; n < 4; ++n)
          acc[m][n] = __builtin_amdgcn_mfma_f32_16x16x32_bf16(af[m], bf[n], acc[m][n], 0, 0, 0);
    }
    __syncthreads();
  }

  #pragma unroll
  for (int m = 0; m < 8; ++m) {
    #pragma unroll
    for (int n = 0; n < 4; ++n) {
      const int gm0 = blockIdx.x * 256 + wr * 128 + m * 16 + lk * 4;
      const int gn  = blockIdx.y * 256 + wc * 64 + n * 16 + lr;
      float v4[4];
      #pragma unroll
      for (int i = 0; i < 4; ++i) {
        float val = acc[m][n][i];
        if (bias) val += bias[gn];
        if (ACT == 1) val = (val > 0.f) ? (val + 1.f) : __builtin_exp2f(val * 1.4426950408889634f);
        if (ACT == 2) {
          const float u = val;
          const float y = 0.7978845608028654f * (u + 0.044715f * u * u * u);
          const float t = 1.0f - 2.0f / (__builtin_exp2f(y * 2.885390081777927f) + 1.0f);
          val = 0.5f * u * (1.0f + t);
        }
        if (RESID) val += resid[(long)(gm0 + i) * ldc + gn];
        v4[i] = val;
      }
      if (OUTMODE == 0) {
        u16* C = (u16*)Cv;
        #pragma unroll
        for (int i = 0; i < 4; ++i) C[(long)(gm0 + i) * ldc + gn] = f2b(v4[i]);
      } else if (OUTMODE == 1) {
        float* C = (float*)Cv;
        #pragma unroll
        for (int i = 0; i < 4; ++i) C[(long)(gm0 + i) * ldc + gn] = v4[i];
      } else {
        u16* C = (u16*)Cv;
        const int b = gm0 >> 11, s = gm0 & 2047;
        const int h = gn >> 7,  d = gn & 127;
        u16x4 p;
        p[0] = f2b(v4[0]); p[1] = f2b(v4[1]); p[2] = f2b(v4[2]); p[3] = f2b(v4[3]);
        *(u16x4*)(C + (long)((b * 16 + h) * 128 + d) * 2048 + s) = p;
      }
    }
  }
}

// ---------------------------------------------------------------------------
// 128x128-tile bt-GEMM (kept for small-N / z-batched uses). See round-2 notes.
// ---------------------------------------------------------------------------
template<int ACT, int OUTMODE, int RESID, int ACCUM, int DIVDEN>
__global__ __launch_bounds__(256) void btgemm_kernel(
    const u16* __restrict__ A, const u16* __restrict__ Bt, void* Cv,
    const float* __restrict__ bias, const float* resid, const float* __restrict__ den,
    int M, int N, int K, int lda, int ldb, int ldc, int ZMOD,
    long sAh, long sAl, long sBh, long sBl, long sCh, long sCl, long sDh, long sDl)
{
  __shared__ char lds[32768];
  char* As = lds;
  char* Bs = lds + 16384;
  const int tid = threadIdx.x;
  const int wave = tid >> 6, lane = tid & 63;
  const int lr = lane & 15, lk = lane >> 4;
  const int wr = wave >> 1, wc = wave & 1;
  const int z = blockIdx.z;
  const int zh = z / ZMOD, zl = z % ZMOD;
  const char* Ab = (const char*)(A + zh * sAh + zl * sAl + (long)blockIdx.x * 128 * lda);
  const char* Bb = (const char*)(Bt + zh * sBh + zl * sBl + (long)blockIdx.y * 128 * ldb);
  const long ldaB = (long)lda * 2, ldbB = (long)ldb * 2;

  f32x4 acc[4][4] = {};

  for (int k0 = 0; k0 < K; k0 += 64) {
    #pragma unroll
    for (int i = 0; i < 4; ++i) {
      const int c = i * 256 + tid;
      const int row = c >> 3;
      const int cb = (c & 7) * 16;
      gload16(Ab + (long)row * ldaB + k0 * 2 + cb, As + c * 16);
      gload16(Bb + (long)row * ldbB + k0 * 2 + cb, Bs + c * 16);
    }
    __syncthreads();
    #pragma unroll
    for (int kk = 0; kk < 64; kk += 32) {
      bf16x8 af[4], bf[4];
      #pragma unroll
      for (int m = 0; m < 4; ++m)
        af[m] = *(const bf16x8*)(As + (wr * 64 + m * 16 + lr) * 128 + (kk + lk * 8) * 2);
      #pragma unroll
      for (int n = 0; n < 4; ++n)
        bf[n] = *(const bf16x8*)(Bs + (wc * 64 + n * 16 + lr) * 128 + (kk + lk * 8) * 2);
      #pragma unroll
      for (int m = 0; m < 4; ++m)
        #pragma unroll
        for (int n = 0; n < 4; ++n)
          acc[m][n] = __builtin_amdgcn_mfma_f32_16x16x32_bf16(af[m], bf[n], acc[m][n], 0, 0, 0);
    }
    __syncthreads();
  }

  const long cbase = (long)zh * sCh + (long)zl * sCl;
  #pragma unroll
  for (int m = 0; m < 4; ++m) {
    #pragma unroll
    for (int n = 0; n < 4; ++n) {
      const int gm0 = blockIdx.x * 128 + wr * 64 + m * 16 + lk * 4;
      const int gn  = blockIdx.y * 128 + wc * 64 + n * 16 + lr;
      float v4[4];
      #pragma unroll
      for (int i = 0; i < 4; ++i) {
        float val = acc[m][n][i];
        if (bias) val += bias[gn];
        if (ACT == 1) val = (val > 0.f) ? (val + 1.f) : __builtin_exp2f(val * 1.4426950408889634f);
        if (ACT == 2) {
          const float u = val;
          const float y = 0.7978845608028654f * (u + 0.044715f * u * u * u);
          const float t = 1.0f - 2.0f / (__builtin_exp2f(y * 2.885390081777927f) + 1.0f);
          val = 0.5f * u * (1.0f + t);
        }
        if (DIVDEN) val = val / (den[(long)zh * sDh + (long)zl * sDl + gm0 + i] + 1e-6f);
        if (RESID) val += resid[cbase + (long)(gm0 + i) * ldc + gn];
        if (ACCUM) val += ((const float*)Cv)[cbase + (long)(gm0 + i) * ldc + gn];
        v4[i] = val;
      }
      if (OUTMODE == 0) {
        u16* C = (u16*)Cv;
        #pragma unroll
        for (int i = 0; i < 4; ++i) C[cbase + (long)(gm0 + i) * ldc + gn] = f2b(v4[i]);
      } else if (OUTMODE == 1) {
        float* C = (float*)Cv;
        #pragma unroll
        for (int i = 0; i < 4; ++i) C[cbase + (long)(gm0 + i) * ldc + gn] = v4[i];
      } else {
        u16* C = (u16*)Cv;
        const int b = gm0 >> 11, s = gm0 & 2047;
        const int h = gn >> 7,  d = gn & 127;
        u16x4 p;
        p[0] = f2b(v4[0]); p[1] = f2b(v4[1]); p[2] = f2b(v4[2]); p[3] = f2b(v4[3]);
        *(u16x4*)(C + (long)((b * 16 + h) * 128 + d) * 2048 + s) = p;
      }
    }
  }
}

// ---------------------------------------------------------------------------
extern "C" void kernel_launch(void* const* d_in, const int* in_sizes, int n_in,
                              void* d_out, int out_size, void* d_ws, size_t ws_size,
                              hipStream_t stream) {
  const float* x   = (const float*)d_in[0];
  const float* Wq  = (const float*)d_in[1];
  const float* bq  = (const float*)d_in[2];
  const float* Wk  = (const float*)d_in[3];
  const float* bk  = (const float*)d_in[4];
  const float* Wv  = (const float*)d_in[5];
  const float* bv  = (const float*)d_in[6];
  const float* Wo  = (const float*)d_in[7];
  const float* bo  = (const float*)d_in[8];
  const float* g1  = (const float*)d_in[9];
  const float* be1 = (const float*)d_in[10];
  const float* g2  = (const float*)d_in[11];
  const float* be2 = (const float*)d_in[12];
  const float* W1  = (const float*)d_in[13];
  const float* b1  = (const float*)d_in[14];
  const float* W2  = (const float*)d_in[15];
  const float* b2  = (const float*)d_in[16];
  const float* W3  = (const float*)d_in[17];
  const float* b3  = (const float*)d_in[18];
  const float* W4  = (const float*)d_in[19];
  const float* b4  = (const float*)d_in[20];
  float* xout = (float*)d_out;
  char* ws = (char*)d_ws;

  // workspace layout (bytes); total ~172.6 MB (same footprint as round 1/2)
  constexpr long DD2 = 2048L * 2048 * 2;          // 8 MB
  constexpr size_t oWqT = 0;
  constexpr size_t oWkT = oWqT + DD2;
  constexpr size_t oWvT = oWkT + DD2;
  constexpr size_t oWoT = oWvT + DD2;
  constexpr size_t oW1T = oWoT + DD2;             // 256x2048 bf16 (1 MB)
  constexpr size_t oW2T = oW1T + 256L * 2048 * 2; // 8192x256 bf16 (4 MB)
  constexpr size_t oW3T = oW2T + 8192L * 256 * 2; // 256x8192 bf16 (4 MB)
  constexpr size_t oW4T = oW3T + 256L * 8192 * 2; // 2048x256 bf16 (1 MB)
  constexpr size_t oH1  = oW4T + 2048L * 256 * 2; // 32MB: h1 / kvpart / attnN / rank-partials
  constexpr size_t oQ   = oH1 + 8192L * 2048 * 2; // 32MB: q / h2 / t3f+t3b
  constexpr size_t oKT  = oQ  + 8192L * 2048 * 2; // 32MB: kT / t1
  constexpr size_t oVT  = oKT + 8192L * 2048 * 2; // 32MB: vT / t2chunk
  constexpr size_t oKVT = oVT + 8192L * 2048 * 2; // 64x128x128 bf16 (2MB)
  constexpr size_t oKS  = oKVT + 64L * 128 * 128 * 2;
  constexpr size_t oDEN = oKS + 64L * 128 * 4;

  u16* WqT = (u16*)(ws + oWqT);
  u16* WkT = (u16*)(ws + oWkT);
  u16* WvT = (u16*)(ws + oWvT);
  u16* WoT = (u16*)(ws + oWoT);
  u16* W1T = (u16*)(ws + oW1T);
  u16* W2T = (u16*)(ws + oW2T);
  u16* W3T = (u16*)(ws + oW3T);
  u16* W4T = (u16*)(ws + oW4T);
  u16* H1    = (u16*)(ws + oH1);    // h1; kv partials; attnN; rank split-K partials
  float* KVP = (float*)(ws + oH1);
  float* RP  = (float*)(ws + oH1);  // rank partials [NP][8192][256] f32
  u16* Qb    = (u16*)(ws + oQ);     // q; h2
  float* T3f = (float*)(ws + oQ);   // after h2 dead: t3 f32 (8MB)
  u16* T3B   = (u16*)(ws + oQ + 8L * 1024 * 1024); // t3 bf16 (4MB)
  u16* KT    = (u16*)(ws + oKT);    // kT; then t1
  u16* T1    = (u16*)(ws + oKT);
  u16* VT    = (u16*)(ws + oVT);    // vT; then t2 chunk
  u16* T2C   = (u16*)(ws + oVT);
  u16* KVT = (u16*)(ws + oKVT);
  float* KS  = (float*)(ws + oKS);
  float* DEN = (float*)(ws + oDEN);
  u16* H2  = Qb;

  const dim3 tb32(32, 8);
  tpose_f32_bf16_kernel<<<dim3(64, 64), tb32, 0, stream>>>(Wq, WqT, 2048, 2048);
  tpose_f32_bf16_kernel<<<dim3(64, 64), tb32, 0, stream>>>(Wk, WkT, 2048, 2048);
  tpose_f32_bf16_kernel<<<dim3(64, 64), tb32, 0, stream>>>(Wv, WvT, 2048, 2048);
  tpose_f32_bf16_kernel<<<dim3(64, 64), tb32, 0, stream>>>(Wo, WoT, 2048, 2048);
  tpose_f32_bf16_kernel<<<dim3(8, 64),  tb32, 0, stream>>>(W1, W1T, 2048, 256);
  tpose_f32_bf16_kernel<<<dim3(256, 8), tb32, 0, stream>>>(W2, W2T, 256, 8192);
  tpose_f32_bf16_kernel<<<dim3(8, 256), tb32, 0, stream>>>(W3, W3T, 8192, 256);
  tpose_f32_bf16_kernel<<<dim3(64, 8),  tb32, 0, stream>>>(W4, W4T, 256, 2048);

  // h1 = LN1(x)
  ln_bf16_kernel<<<8192, 256, 0, stream>>>(x, g1, be1, H1);

  // q,k,v projections on 256^2 tile (grid 32x8 = 256 blocks)
  btgemm256_kernel<1, 0, 0><<<dim3(32, 8), 512, 0, stream>>>(
      H1, WqT, Qb, bq, nullptr, 2048, 2048, 2048, 2048);
  btgemm256_kernel<1, 2, 0><<<dim3(32, 8), 512, 0, stream>>>(
      H1, WkT, KT, bk, nullptr, 2048, 2048, 2048, 2048);
  btgemm256_kernel<0, 2, 0><<<dim3(32, 8), 512, 0, stream>>>(
      H1, WvT, VT, bv, nullptr, 2048, 2048, 2048, 2048);

  // ksum over S, den = q.ksum
  ksum_kernel<<<2048, 256, 0, stream>>>(KT, KS);
  den_kernel<<<8192, 256, 0, stream>>>(Qb, KS, DEN);

  // kv split-K (z = head*8 + K-chunk of 256) -> f32 partials -> reduce
  btgemm_kernel<0, 1, 0, 0, 0><<<dim3(1, 1, 512), 256, 0, stream>>>(
      VT, KT, KVP, nullptr, nullptr, nullptr, 128, 128, 256, 2048, 2048, 128, 8,
      262144, 256, 262144, 256, 16384, 1048576, 0, 0);
  kvreduce_kernel<<<1024, 256, 0, stream>>>(KVP, KVT);

  // num = q @ kvT ; /(den+eps) -> attnN (bf16, (B,S,D), into H1 region)
  btgemm_kernel<0, 0, 0, 0, 1><<<dim3(16, 1, 64), 256, 0, stream>>>(
      Qb, KVT, H1, nullptr, nullptr, DEN, 2048, 128, 128, 2048, 128, 2048, 16,
      4194304, 128, 262144, 16384, 4194304, 128, 32768, 2048);

  // x2 = x + attnN@Wo + bo -> d_out (f32)
  btgemm256_kernel<0, 1, 1><<<dim3(32, 8), 512, 0, stream>>>(
      H1, WoT, xout, bo, x, 2048, 2048, 2048, 2048);

  // h2 = LN2(x2)
  ln_bf16_kernel<<<8192, 256, 0, stream>>>(xout, g2, be2, H2);

  // t1 = h2@W1 + b1 : split-K x4 (K-sub 512, grid 512 blocks) -> reduce bf16
  btgemm_kernel<0, 1, 0, 0, 0><<<dim3(64, 2, 4), 256, 0, stream>>>(
      H2, W1T, RP, nullptr, nullptr, nullptr, 8192, 256, 512, 2048, 2048, 256, 4,
      0, 512, 0, 512, 0, 2097152, 0, 0);
  rankreduce_kernel<4, 0, 0><<<2048, 256, 0, stream>>>(RP, b1, T1);

  // FFN middle, 4 HID-chunks of 2048:
  //   t2c = gelu(t1@W2c+b2c) [256^2 tile]; t3f (+)= t2c@W3c [split-K x2 + reduce]
  for (int c = 0; c < 4; ++c) {
    btgemm256_kernel<2, 0, 0><<<dim3(32, 8), 512, 0, stream>>>(
        T1, W2T + (long)c * 2048 * 256, T2C, b2 + c * 2048, nullptr,
        256, 256, 256, 2048);
    btgemm_kernel<0, 1, 0, 0, 0><<<dim3(64, 2, 2), 256, 0, stream>>>(
        T2C, W3T + (long)c * 2048, RP, nullptr, nullptr, nullptr,
        8192, 256, 1024, 2048, 8192, 256, 2,
        0, 1024, 0, 1024, 0, 2097152, 0, 0);
    if (c == 0)
      rankreduce_kernel<2, 1, 0><<<2048, 256, 0, stream>>>(RP, b3, T3f);
    else
      rankreduce_kernel<2, 1, 1><<<2048, 256, 0, stream>>>(RP, nullptr, T3f);
  }

  // t3 -> bf16
  cvt_f32_bf16_kernel<<<2048, 256, 0, stream>>>(T3f, T3B, 8192L * 256);

  // out = x2 + t3@W4 + b4   (resid = d_out itself)
  btgemm256_kernel<0, 1, 1><<<dim3(32, 8), 512, 0, stream>>>(
      T3B, W4T, xout, b4, xout, 256, 256, 256, 2048);
}